// Round 9
// baseline (420.178 us; speedup 1.0000x reference)
//
#include <hip/hip_runtime.h>
#include <hip/hip_fp16.h>
#include <hip/hip_cooperative_groups.h>
#include <math.h>

#define NEG_SLOPE 0.01f
#define BKT_BITS 7        // 128 nodes per bucket
#define BKT_MASK 127
#define PG 256            // prep grid blocks (== SBLOCKS for the multisplit)
#define PT 512            // prep threads per block

// ---------------- one cooperative prep kernel ----------------
// Replaces 7 launches (~12us overhead each): stconv+hist | scan1 | scan2 | scan3
// | multisplit | csr_build, separated by grid.sync().

struct PrepArgs {
    const int* dst; const int* src; const float* h0; const float* att_w;
    int* blockhist; int* local_ex; int* partials; int* bh_scan;
    unsigned* pairs; int* row_ptr; int* csr_src;
    float* s1; float* t1; __half* hA;
    int N, E, NB, chunk, n2, nch;
};

__global__ void __launch_bounds__(PT) prep_coop(PrepArgs A) {
    cooperative_groups::grid_group grid = cooperative_groups::this_grid();
    __shared__ int smem[1024];
    int b = blockIdx.x, tid = threadIdx.x;

    // ---- P0a: stconv — wave per node, grid-stride (s1/t1 + fp16 copy of h0)
    {
        int lane = tid & 63;
        int wv = b * (PT / 64) + (tid >> 6);
        for (int v = wv; v < A.N; v += PG * (PT / 64)) {
            float2 hv = ((const float2*)(A.h0 + (size_t)v * 128))[lane];
            ((__half2*)(A.hA + (size_t)v * 128))[lane] = __floats2half2_rn(hv.x, hv.y);
            float2 wsv = ((const float2*)A.att_w)[lane];
            float2 wdv = ((const float2*)(A.att_w + 128))[lane];
            float ps = hv.x * wsv.x + hv.y * wsv.y;
            float pt = hv.x * wdv.x + hv.y * wdv.y;
            for (int off = 32; off > 0; off >>= 1) {
                ps += __shfl_down(ps, off);
                pt += __shfl_down(pt, off);
            }
            if (lane == 0) { A.s1[v] = ps; A.t1[v] = pt; }
        }
    }
    // ---- P0b: per-(block,bucket) histogram of dst>>7
    for (int k = tid; k < A.NB; k += PT) smem[k] = 0;
    __syncthreads();
    {
        int beg = b * A.chunk, endq = min(A.E, beg + A.chunk);
        for (int e = beg + tid; e < endq; e += PT)
            atomicAdd(&smem[A.dst[e] >> BKT_BITS], 1);
    }
    __syncthreads();
    for (int k = tid; k < A.NB; k += PT) A.blockhist[k * PG + b] = smem[k];
    grid.sync();

    // ---- P1: per-512-chunk scan of the n2 count matrix
    if (b < A.nch) {
        int i = b * PT + tid;
        int x = (i < A.n2) ? A.blockhist[i] : 0;
        smem[tid] = x;
        __syncthreads();
        for (int off = 1; off < PT; off <<= 1) {
            int y = (tid >= off) ? smem[tid - off] : 0;
            __syncthreads();
            smem[tid] += y;
            __syncthreads();
        }
        if (i < A.n2) A.local_ex[i] = smem[tid] - x;
        if (tid == PT - 1) A.partials[b] = smem[PT - 1];
    }
    grid.sync();

    // ---- P2: block 0 scans the nch (<=512) chunk totals
    if (b == 0) {
        int x = (tid < A.nch) ? A.partials[tid] : 0;
        smem[tid] = x;
        __syncthreads();
        for (int off = 1; off < PT; off <<= 1) {
            int y = (tid >= off) ? smem[tid - off] : 0;
            __syncthreads();
            smem[tid] += y;
            __syncthreads();
        }
        if (tid < A.nch) A.partials[tid] = smem[tid] - x;
        if (tid == PT - 1) A.partials[A.nch] = smem[PT - 1];
    }
    grid.sync();

    // ---- P3: add chunk offsets -> bh_scan; bh_scan[n2] = E
    for (int i = b * PT + tid; i < A.n2; i += PG * PT)
        A.bh_scan[i] = A.local_ex[i] + A.partials[i >> 9];   // PT == 512 == 2^9
    if (b == 0 && tid == 0) A.bh_scan[A.n2] = A.partials[A.nch];
    grid.sync();

    // ---- P4: multisplit — packed (src<<7)|(dst&127) into (block,bucket) segments
    {
        int* lbase = smem;
        int* lcnt  = smem + A.NB;
        for (int k = tid; k < A.NB; k += PT) {
            lbase[k] = A.bh_scan[k * PG + b];
            lcnt[k]  = 0;
        }
        __syncthreads();
        int beg = b * A.chunk, endq = min(A.E, beg + A.chunk);
        for (int e = beg + tid; e < endq; e += PT) {
            int d = A.dst[e];
            int k = d >> BKT_BITS;
            int pos = lbase[k] + atomicAdd(&lcnt[k], 1);
            A.pairs[pos] = ((unsigned)A.src[e] << BKT_BITS) | (unsigned)(d & BKT_MASK);
        }
    }
    grid.sync();

    // ---- P5: per-bucket CSR build (blocks grid-stride over buckets)
    for (int k = b; k < A.NB; k += PG) {
        int* ldeg  = smem;
        int* lscan = smem + 128;
        int* lpos  = smem + 256;
        int bbase = A.bh_scan[k * PG];
        int bend  = A.bh_scan[(k + 1) * PG];   // k==NB-1 reads bh_scan[n2]==E
        __syncthreads();                        // smem reuse across k iterations
        if (tid < 128) ldeg[tid] = 0;
        __syncthreads();
        for (int i = bbase + tid; i < bend; i += PT)
            atomicAdd(&ldeg[A.pairs[i] & BKT_MASK], 1);
        __syncthreads();
        int x = (tid < 128) ? ldeg[tid] : 0;
        if (tid < 128) lscan[tid] = x;
        __syncthreads();
        for (int off = 1; off < 128; off <<= 1) {
            int y = 0;
            if (tid < 128 && tid >= off) y = lscan[tid - off];
            __syncthreads();
            if (tid < 128) lscan[tid] += y;
            __syncthreads();
        }
        if (tid < 128) {
            int excl = lscan[tid] - x;
            int node = (k << BKT_BITS) + tid;
            if (node < A.N) A.row_ptr[node] = bbase + excl;
            lpos[tid] = excl;
        }
        __syncthreads();
        for (int i = bbase + tid; i < bend; i += PT) {
            unsigned p = A.pairs[i];
            int pos = atomicAdd(&lpos[p & BKT_MASK], 1);
            A.csr_src[bbase + pos] = (int)(p >> BKT_BITS);
        }
    }
    if (b == 0 && tid == 0) A.row_ptr[A.N] = A.E;
}

// ---------------- aggregation ----------------

__device__ __forceinline__ void gath(const __half* __restrict__ hin, int uu, float wgt,
                                     int sub, float4& acc) {
    float2 r = ((const float2*)(hin + (size_t)uu * 128))[sub];   // 4 fp16 dims
    float2 f01 = __half22float2(*(const __half2*)&r.x);
    float2 f23 = __half22float2(*(const __half2*)&r.y);
    acc.x = fmaf(wgt, f01.x, acc.x); acc.y = fmaf(wgt, f01.y, acc.y);
    acc.z = fmaf(wgt, f23.x, acc.z); acc.w = fmaf(wgt, f23.y, acc.w);
}

// HALF-WAVE per node (2 nodes/wave): 32 lanes x 4 dims = full 128-dim row per half,
// so no cross-half acc combine. Tile = 32 edges (matches mean degree 32): metadata
// lanes fully used, 1 variable-lane shuffle pair per edge (was 2/edge at tile 64).
// Unnormalized sum (bounded logits -> no overflow), scale by 1/lsum at end.
template<bool LAST>
__global__ void agg_kernel(const __half* __restrict__ hin, const float* __restrict__ s,
                           const float* __restrict__ t, const int* __restrict__ row_ptr,
                           const int* __restrict__ csr_src, int E,
                           __half* __restrict__ hout16, float* __restrict__ outf,
                           const float* __restrict__ att_w_next,
                           float* __restrict__ s2, float* __restrict__ t2, int n) {
    int gid   = blockIdx.x * blockDim.x + threadIdx.x;
    int lane  = threadIdx.x & 63;
    int half  = lane >> 5;
    int sub   = lane & 31;
    int v     = (gid >> 6) * 2 + half;        // one node per half-wave
    bool valid = (v < n);
    int vc    = valid ? v : (n - 1);
    int beg = row_ptr[vc];
    int end = row_ptr[vc + 1];
    if (!valid) end = beg;
    float tv = t[vc];

    int tiles = (end - beg + 31) >> 5;
    tiles = max(tiles, __shfl_xor(tiles, 32));   // wave-uniform trip count

    float4 acc = make_float4(0.f, 0.f, 0.f, 0.f);
    float lsum = 0.f;
    int hbase = half << 5;
    for (int j = 0; j < tiles; ++j) {
        int base = beg + (j << 5);
        int cnt = end - base;                  // <=0 when this half is exhausted
        cnt = min(max(cnt, 0), 32);
        int idx = base + min(sub, max(cnt - 1, 0));
        idx = min(idx, E - 1);                 // safety clamp; wl=0 masks garbage
        int u = csr_src[idx];
        float a = s[u] + tv;
        float e = (a > 0.f) ? a : NEG_SLOPE * a;
        float wl = (sub < cnt) ? __expf(e) : 0.f;
        lsum += wl;
        int kmax = max(cnt, __shfl_xor(cnt, 32));   // wave-uniform
        int k = 0;
        for (; k + 1 < kmax; k += 2) {
            int   u0 = __shfl(u,  hbase + k);
            float w0 = __shfl(wl, hbase + k);
            int   u1 = __shfl(u,  hbase + k + 1);
            float w1 = __shfl(wl, hbase + k + 1);
            gath(hin, u0, w0, sub, acc);
            gath(hin, u1, w1, sub, acc);
        }
        if (k < kmax) {
            int   u0 = __shfl(u,  hbase + k);
            float w0 = __shfl(wl, hbase + k);
            gath(hin, u0, w0, sub, acc);
        }
    }
    // lsum reduce WITHIN the half (xor offsets <32 never cross the 32-lane group)
    for (int off = 16; off > 0; off >>= 1) lsum += __shfl_xor(lsum, off);
    float inv_l = (lsum > 0.f) ? (1.0f / lsum) : 0.f;   // deg-0 -> zero row
    acc.x *= inv_l; acc.y *= inv_l; acc.z *= inv_l; acc.w *= inv_l;

    if (LAST) {
        if (valid) ((float4*)(outf + (size_t)v * 128))[sub] = acc;
    } else {
        if (valid) {
            __half2 q01 = __floats2half2_rn(acc.x, acc.y);
            __half2 q23 = __floats2half2_rn(acc.z, acc.w);
            float2 packed;
            packed.x = *(const float*)&q01;
            packed.y = *(const float*)&q23;
            ((float2*)(hout16 + (size_t)v * 128))[sub] = packed;
        }
        // fused next-layer s/t: per-half dot of the full row with next weights
        float4 ws4 = ((const float4*)att_w_next)[sub];
        float4 wd4 = ((const float4*)(att_w_next + 128))[sub];
        float ps = acc.x * ws4.x + acc.y * ws4.y + acc.z * ws4.z + acc.w * ws4.w;
        float pt = acc.x * wd4.x + acc.y * wd4.y + acc.z * wd4.z + acc.w * wd4.w;
        for (int off = 16; off > 0; off >>= 1) {   // within-half butterfly
            ps += __shfl_xor(ps, off);
            pt += __shfl_xor(pt, off);
        }
        if (valid && sub == 0) { s2[v] = ps; t2[v] = pt; }
    }
}

// ---------------- launch ----------------

extern "C" void kernel_launch(void* const* d_in, const int* in_sizes, int n_in,
                              void* d_out, int out_size, void* d_ws, size_t ws_size,
                              hipStream_t stream) {
    const float* h0    = (const float*)d_in[0];
    const int*   src   = (const int*)d_in[1];
    const int*   dst   = (const int*)d_in[2];
    const float* att_w = (const float*)d_in[3];
    int N = in_sizes[0] / 128;
    int E = in_sizes[1];
    int L = in_sizes[3] / 256;
    float* out = (float*)d_out;

    int NB = (N + BKT_MASK) >> BKT_BITS;     // 391 buckets
    int n2 = NB * PG;                        // 100096 count-matrix entries
    int chunk = (E + PG - 1) / PG;
    int nch = (n2 + PT - 1) / PT;            // 196 scan chunks (<= 512 required)

    char* ws = (char*)d_ws;
    size_t off = 0;
    auto alloc = [&](size_t bytes) -> void* {
        void* p = ws + off;
        off = (off + bytes + 511) & ~(size_t)511;
        return p;
    };
    int*      row_ptr   = (int*)     alloc((size_t)(N + 1) * 4);
    int*      csr_src   = (int*)     alloc((size_t)E * 4);
    float*    s1        = (float*)   alloc((size_t)N * 4);
    float*    t1        = (float*)   alloc((size_t)N * 4);
    float*    s2        = (float*)   alloc((size_t)N * 4);
    float*    t2        = (float*)   alloc((size_t)N * 4);
    __half*   hA        = (__half*)  alloc((size_t)N * 128 * 2);
    __half*   hB        = (__half*)  alloc((size_t)N * 128 * 2);
    unsigned* pairs     = (unsigned*)alloc((size_t)E * 4);
    int*      blockhist = (int*)     alloc((size_t)n2 * 4);
    int*      bh_scan   = (int*)     alloc((size_t)(n2 + 1) * 4);
    int*      local_ex  = (int*)     alloc((size_t)n2 * 4);
    int*      partials  = (int*)     alloc(1025 * 4);

    PrepArgs A;
    A.dst = dst; A.src = src; A.h0 = h0; A.att_w = att_w;
    A.blockhist = blockhist; A.local_ex = local_ex; A.partials = partials;
    A.bh_scan = bh_scan; A.pairs = pairs; A.row_ptr = row_ptr; A.csr_src = csr_src;
    A.s1 = s1; A.t1 = t1; A.hA = hA;
    A.N = N; A.E = E; A.NB = NB; A.chunk = chunk; A.n2 = n2; A.nch = nch;
    void* kargs[] = { &A };
    hipLaunchCooperativeKernel((void*)prep_coop, dim3(PG), dim3(PT), kargs, 0, stream);

    const int tb = 256;
    int npairs = (N + 1) / 2;                        // 2 nodes per wave
    int node_blocks = (npairs * 64 + tb - 1) / tb;

    __half* hin = hA;
    __half* hnx = hB;
    float *sc = s1, *tc = t1, *sn = s2, *tn = t2;
    for (int l = 0; l < L; ++l) {
        if (l == L - 1) {
            agg_kernel<true><<<node_blocks, tb, 0, stream>>>(
                hin, sc, tc, row_ptr, csr_src, E, nullptr, out, nullptr, nullptr, nullptr, N);
        } else {
            agg_kernel<false><<<node_blocks, tb, 0, stream>>>(
                hin, sc, tc, row_ptr, csr_src, E, hnx, nullptr,
                att_w + (size_t)(l + 1) * 256, sn, tn, N);
            __half* tmp = hin; hin = hnx; hnx = tmp;
            float* tf;
            tf = sc; sc = sn; sn = tf;
            tf = tc; tc = tn; tn = tf;
        }
    }
}

// Round 10
// 275.400 us; speedup vs baseline: 1.5257x; 1.5257x over previous
//
#include <hip/hip_runtime.h>
#include <hip/hip_fp16.h>
#include <math.h>

#define NEG_SLOPE 0.01f
#define BKT_BITS 7        // 128 nodes per bucket
#define BKT_MASK 127
#define PG   256          // multisplit blocks (1 block/CU, 8 waves each)
#define PT   512          // threads per multisplit block
// NOTE: cooperative grid.sync fusion (round 9) was a 93us REGRESSION — 23% occupancy,
// VALUBusy 1.7% (spin-wait). Separate graph-replayed launches are cheaper. Do not redo.

// ---- A: stconv (wave/node, grid-stride) + per-(block,bucket) dst histogram ----
__global__ void __launch_bounds__(PT) stconv_hist_kernel(
        const float* __restrict__ h0, const float* __restrict__ att_w,
        float* __restrict__ s1, float* __restrict__ t1, __half* __restrict__ hA,
        const int* __restrict__ dst, int* __restrict__ blockhist, int* __restrict__ done,
        int N, int E, int NB, int chunk) {
    __shared__ int lh[512];                    // NB <= 512
    int b = blockIdx.x, tid = threadIdx.x;
    if (b == 0 && tid == 0) *done = 0;         // reset for scan12's last-block pattern
    // stconv: s1/t1 + fp16 copy of h0
    {
        int lane = tid & 63;
        float2 wsv = ((const float2*)att_w)[lane];
        float2 wdv = ((const float2*)(att_w + 128))[lane];
        for (int v = b * (PT / 64) + (tid >> 6); v < N; v += PG * (PT / 64)) {
            float2 hv = ((const float2*)(h0 + (size_t)v * 128))[lane];
            ((__half2*)(hA + (size_t)v * 128))[lane] = __floats2half2_rn(hv.x, hv.y);
            float ps = hv.x * wsv.x + hv.y * wsv.y;
            float pt = hv.x * wdv.x + hv.y * wdv.y;
            for (int off = 32; off > 0; off >>= 1) {
                ps += __shfl_down(ps, off);
                pt += __shfl_down(pt, off);
            }
            if (lane == 0) { s1[v] = ps; t1[v] = pt; }
        }
    }
    // histogram of dst>>7 over this block's edge chunk
    for (int k = tid; k < NB; k += PT) lh[k] = 0;
    __syncthreads();
    int beg = b * chunk, end = min(E, beg + chunk);
    for (int e = beg + tid; e < end; e += PT)
        atomicAdd(&lh[dst[e] >> BKT_BITS], 1);
    __syncthreads();
    for (int k = tid; k < NB; k += PT) blockhist[k * PG + b] = lh[k];
}

// ---- B: scan1 + fused scan2 (last-block-done, device-scope fence+atomic) ----
__global__ void scan12_kernel(const int* __restrict__ in, int* __restrict__ local_excl,
                              int* __restrict__ partials, int* __restrict__ coff,
                              int* __restrict__ done, int n, int nch) {
    __shared__ int sm[1024];
    __shared__ int amlast;
    int i = blockIdx.x * 1024 + threadIdx.x;
    int x = (i < n) ? in[i] : 0;
    sm[threadIdx.x] = x;
    __syncthreads();
    for (int off = 1; off < 1024; off <<= 1) {
        int y = (threadIdx.x >= (unsigned)off) ? sm[threadIdx.x - off] : 0;
        __syncthreads();
        sm[threadIdx.x] += y;
        __syncthreads();
    }
    if (i < n) local_excl[i] = sm[threadIdx.x] - x;
    if (threadIdx.x == 1023) partials[blockIdx.x] = sm[1023];
    __threadfence();                           // release partials (device scope)
    __syncthreads();
    if (threadIdx.x == 0) amlast = (atomicAdd(done, 1) == nch - 1);
    __syncthreads();
    if (!amlast) return;
    __threadfence();                           // acquire other blocks' partials
    int p = (threadIdx.x < (unsigned)nch) ? partials[threadIdx.x] : 0;
    sm[threadIdx.x] = p;
    __syncthreads();
    for (int off = 1; off < 1024; off <<= 1) {
        int y = (threadIdx.x >= (unsigned)off) ? sm[threadIdx.x - off] : 0;
        __syncthreads();
        sm[threadIdx.x] += y;
        __syncthreads();
    }
    if (threadIdx.x < (unsigned)nch) coff[threadIdx.x] = sm[threadIdx.x] - p;
    if (threadIdx.x == 1023) coff[nch] = sm[1023];
}

// ---- C: multisplit; segment base = local_ex + coff (scan3 inlined) ----
__global__ void __launch_bounds__(PT) bksplit_kernel(
        const int* __restrict__ src, const int* __restrict__ dst,
        const int* __restrict__ local_ex, const int* __restrict__ coff,
        unsigned* __restrict__ pairs, int E, int NB, int chunk) {
    __shared__ int lbase[512];
    __shared__ int lcnt[512];
    int b = blockIdx.x, tid = threadIdx.x;
    for (int k = tid; k < NB; k += PT) {
        int idx = k * PG + b;
        lbase[k] = local_ex[idx] + coff[idx >> 10];
        lcnt[k]  = 0;
    }
    __syncthreads();
    int beg = b * chunk, end = min(E, beg + chunk);
    for (int e = beg + tid; e < end; e += PT) {
        int d = dst[e];
        int k = d >> BKT_BITS;
        int pos = lbase[k] + atomicAdd(&lcnt[k], 1);
        pairs[pos] = ((unsigned)src[e] << BKT_BITS) | (unsigned)(d & BKT_MASK);
    }
}

// ---- D: per-bucket CSR build; bucket bounds from local_ex + coff ----
__global__ void csr_build_kernel(const unsigned* __restrict__ pairs,
                                 const int* __restrict__ local_ex, const int* __restrict__ coff,
                                 int* __restrict__ row_ptr, int* __restrict__ csr_src,
                                 int E, int N, int NB) {
    __shared__ int ldeg[128];
    __shared__ int lscan[128];
    __shared__ int lpos[128];
    int k = blockIdx.x, tid = threadIdx.x;
    int i0 = k * PG;
    int bbase = local_ex[i0] + coff[i0 >> 10];
    int bend;
    if (k == NB - 1) bend = E;
    else { int i1 = (k + 1) * PG; bend = local_ex[i1] + coff[i1 >> 10]; }
    if (tid < 128) ldeg[tid] = 0;
    __syncthreads();
    for (int i = bbase + tid; i < bend; i += blockDim.x)
        atomicAdd(&ldeg[pairs[i] & BKT_MASK], 1);
    __syncthreads();
    int x = (tid < 128) ? ldeg[tid] : 0;
    if (tid < 128) lscan[tid] = x;
    __syncthreads();
    for (int off = 1; off < 128; off <<= 1) {
        int y = 0;
        if (tid < 128 && tid >= off) y = lscan[tid - off];
        __syncthreads();
        if (tid < 128) lscan[tid] += y;
        __syncthreads();
    }
    if (tid < 128) {
        int excl = lscan[tid] - x;
        int node = (k << BKT_BITS) + tid;
        if (node < N) row_ptr[node] = bbase + excl;
        lpos[tid] = excl;
    }
    if (k == NB - 1 && tid == 0) row_ptr[N] = E;
    __syncthreads();
    for (int i = bbase + tid; i < bend; i += blockDim.x) {
        unsigned p = pairs[i];
        int pos = atomicAdd(&lpos[p & BKT_MASK], 1);
        csr_src[bbase + pos] = (int)(p >> BKT_BITS);
    }
}

// ---------------- aggregation (round-8 verbatim: known 59us, passed) ----------------

__device__ __forceinline__ void gath(const __half* __restrict__ hin, int uu, float wgt,
                                     int hlane, float4& acc) {
    float2 r = ((const float2*)(hin + (size_t)uu * 128))[hlane];   // 4 fp16 dims
    float2 f01 = __half22float2(*(const __half2*)&r.x);
    float2 f23 = __half22float2(*(const __half2*)&r.y);
    acc.x = fmaf(wgt, f01.x, acc.x); acc.y = fmaf(wgt, f01.y, acc.y);
    acc.z = fmaf(wgt, f23.x, acc.z); acc.w = fmaf(wgt, f23.y, acc.w);
}

template<bool LAST>
__global__ void agg_kernel(const __half* __restrict__ hin, const float* __restrict__ s,
                           const float* __restrict__ t, const int* __restrict__ row_ptr,
                           const int* __restrict__ csr_src,
                           __half* __restrict__ hout16, float* __restrict__ outf,
                           const float* __restrict__ att_w_next,
                           float* __restrict__ s2, float* __restrict__ t2, int n) {
    int gid   = blockIdx.x * blockDim.x + threadIdx.x;
    int v     = gid >> 6;
    int lane  = threadIdx.x & 63;
    if (v >= n) return;
    int half  = lane >> 5;
    int hlane = lane & 31;

    int beg = row_ptr[v];
    int end = row_ptr[v + 1];
    float tv = t[v];

    float4 acc = make_float4(0.f, 0.f, 0.f, 0.f);
    float lsum_l = 0.f;

    for (int base = beg; base < end; base += 64) {
        int cnt = end - base;
        if (cnt > 64) cnt = 64;
        int idx = base + min(lane, cnt - 1);
        int u   = csr_src[idx];
        float a = s[u] + tv;
        float e = (a > 0.f) ? a : NEG_SLOPE * a;
        float wl = (lane < cnt) ? __expf(e) : 0.f;
        lsum_l += wl;
        int steps = (cnt + 1) >> 1;
        int k = 0;
        for (; k + 1 < steps; k += 2) {
            int sl0 = (k << 1) + half;
            int sl1 = (k << 1) + 2 + half;
            int   u0 = __shfl(u, sl0);
            float w0 = __shfl(wl, sl0);
            int   u1 = __shfl(u, sl1);
            float w1 = __shfl(wl, sl1);
            gath(hin, u0, w0, hlane, acc);
            gath(hin, u1, w1, hlane, acc);
        }
        if (k < steps) {
            int sl = (k << 1) + half;
            int   u0 = __shfl(u, sl);
            float w0 = __shfl(wl, sl);
            gath(hin, u0, w0, hlane, acc);
        }
    }
    float lsum = lsum_l;
    for (int off = 32; off > 0; off >>= 1) lsum += __shfl_xor(lsum, off);
    acc.x += __shfl_xor(acc.x, 32);
    acc.y += __shfl_xor(acc.y, 32);
    acc.z += __shfl_xor(acc.z, 32);
    acc.w += __shfl_xor(acc.w, 32);
    float inv_l = (lsum > 0.f) ? (1.0f / lsum) : 0.f;   // deg-0 -> zero row
    acc.x *= inv_l; acc.y *= inv_l; acc.z *= inv_l; acc.w *= inv_l;

    if (LAST) {
        if (half == 0)
            ((float4*)(outf + (size_t)v * 128))[hlane] = acc;
    } else {
        if (half == 0) {
            __half2 q01 = __floats2half2_rn(acc.x, acc.y);
            __half2 q23 = __floats2half2_rn(acc.z, acc.w);
            float2 packed;
            packed.x = *(const float*)&q01;
            packed.y = *(const float*)&q23;
            ((float2*)(hout16 + (size_t)v * 128))[hlane] = packed;
        }
        float4 ws4 = ((const float4*)att_w_next)[hlane];
        float4 wd4 = ((const float4*)(att_w_next + 128))[hlane];
        float ps = acc.x * ws4.x + acc.y * ws4.y + acc.z * ws4.z + acc.w * ws4.w;
        float pt = acc.x * wd4.x + acc.y * wd4.y + acc.z * wd4.z + acc.w * wd4.w;
        for (int off = 16; off > 0; off >>= 1) {
            ps += __shfl_down(ps, off);
            pt += __shfl_down(pt, off);
        }
        if (lane == 0) { s2[v] = ps; t2[v] = pt; }
    }
}

// ---------------- launch ----------------

extern "C" void kernel_launch(void* const* d_in, const int* in_sizes, int n_in,
                              void* d_out, int out_size, void* d_ws, size_t ws_size,
                              hipStream_t stream) {
    const float* h0    = (const float*)d_in[0];
    const int*   src   = (const int*)d_in[1];
    const int*   dst   = (const int*)d_in[2];
    const float* att_w = (const float*)d_in[3];
    int N = in_sizes[0] / 128;
    int E = in_sizes[1];
    int L = in_sizes[3] / 256;
    float* out = (float*)d_out;

    int NB = (N + BKT_MASK) >> BKT_BITS;     // 391 buckets
    int n2 = NB * PG;                        // 100096 count-matrix entries
    int chunk = (E + PG - 1) / PG;
    int nch = (n2 + 1023) / 1024;            // 98 scan chunks (<= 1024 required)

    char* ws = (char*)d_ws;
    size_t off = 0;
    auto alloc = [&](size_t bytes) -> void* {
        void* p = ws + off;
        off = (off + bytes + 511) & ~(size_t)511;
        return p;
    };
    int*      row_ptr   = (int*)     alloc((size_t)(N + 1) * 4);
    int*      csr_src   = (int*)     alloc((size_t)E * 4);
    float*    s1        = (float*)   alloc((size_t)N * 4);
    float*    t1        = (float*)   alloc((size_t)N * 4);
    float*    s2        = (float*)   alloc((size_t)N * 4);
    float*    t2        = (float*)   alloc((size_t)N * 4);
    __half*   hA        = (__half*)  alloc((size_t)N * 128 * 2);
    __half*   hB        = (__half*)  alloc((size_t)N * 128 * 2);
    unsigned* pairs     = (unsigned*)alloc((size_t)E * 4);
    int*      blockhist = (int*)     alloc((size_t)n2 * 4);
    int*      local_ex  = (int*)     alloc((size_t)n2 * 4);
    int*      partials  = (int*)     alloc((size_t)(nch + 1) * 4);
    int*      coff      = (int*)     alloc((size_t)(nch + 1) * 4);
    int*      done      = (int*)     alloc(4);

    stconv_hist_kernel<<<PG, PT, 0, stream>>>(h0, att_w, s1, t1, hA,
                                              dst, blockhist, done, N, E, NB, chunk);
    scan12_kernel<<<nch, 1024, 0, stream>>>(blockhist, local_ex, partials, coff, done, n2, nch);
    bksplit_kernel<<<PG, PT, 0, stream>>>(src, dst, local_ex, coff, pairs, E, NB, chunk);
    csr_build_kernel<<<NB, 512, 0, stream>>>(pairs, local_ex, coff, row_ptr, csr_src, E, N, NB);

    const int tb = 256;
    int node_blocks = (N * 64 + tb - 1) / tb;        // one wave per node

    __half* hin = hA;
    __half* hnx = hB;
    float *sc = s1, *tc = t1, *sn = s2, *tn = t2;
    for (int l = 0; l < L; ++l) {
        if (l == L - 1) {
            agg_kernel<true><<<node_blocks, tb, 0, stream>>>(
                hin, sc, tc, row_ptr, csr_src, nullptr, out, nullptr, nullptr, nullptr, N);
        } else {
            agg_kernel<false><<<node_blocks, tb, 0, stream>>>(
                hin, sc, tc, row_ptr, csr_src, hnx, nullptr,
                att_w + (size_t)(l + 1) * 256, sn, tn, N);
            __half* tmp = hin; hin = hnx; hnx = tmp;
            float* tf;
            tf = sc; sc = sn; sn = tf;
            tf = tc; tc = tn; tn = tf;
        }
    }
}